// Round 1
// baseline (9090.673 us; speedup 1.0000x reference)
//
#include <hip/hip_runtime.h>

// FastGRNN: T=512 B=256 D=256 H=1024 RW=RU=64, all fp32.
// Structure:
//   wx_kernel : d_out[t,b,:] = (x[t,b,:] @ W1^T) @ W2^T   (feed-forward, all t)
//   rec_kernel: per-batch-row independent scan, persistent WG owns 2 rows,
//               h in LDS, U1/U2 streamed from L2 each step, d_out[t] is read
//               (wx) and overwritten (h_t) in place by the same thread.

constexpr int T_ = 512;
constexpr int B_ = 256;
constexpr int D_ = 256;
constexpr int H_ = 1024;
constexpr int RW_ = 64;
constexpr int RU_ = 64;
constexpr int M_ = T_ * B_;      // 131072 rows of x / wx
constexpr int ROWS_AB = 16;      // x-rows per workgroup in wx_kernel
constexpr int GC = 128;          // workgroups in rec_kernel
constexpr int RPW = B_ / GC;     // 2 batch rows per workgroup

__global__ __launch_bounds__(256) void wx_kernel(
    const float* __restrict__ x,   // [M, D]
    const float* __restrict__ W1,  // [RW, D]
    const float* __restrict__ W2,  // [H, RW]
    float* __restrict__ out)       // [M, H] <- wx
{
    __shared__ float xs[ROWS_AB][D_];         // 16 KB x tile
    __shared__ float xw1s[ROWS_AB][RW_ + 4];  // pad 68 (272B row stride, 16B aligned)

    const int tid = threadIdx.x;
    const int m0 = blockIdx.x * ROWS_AB;

    // stage x tile (16 rows x 256) as float4, coalesced
    {
        const float4* xg = (const float4*)(x + (size_t)m0 * D_);
        float4* xsv = (float4*)&xs[0][0];
#pragma unroll
        for (int k = 0; k < 4; ++k) xsv[tid + 256 * k] = xg[tid + 256 * k];
    }
    __syncthreads();

    const int r = tid & 63;       // 64 lanes over rank / j dims
    const int rowgrp = tid >> 6;  // 4 row groups

    // phase A: xw1[row][r] = sum_d x[row,d] * W1[r,d]; W1 streamed (L2-hot)
    {
        float acc[4] = {0.f, 0.f, 0.f, 0.f};
        const float4* w1p = (const float4*)(W1 + (size_t)r * D_);
#pragma unroll 4
        for (int k = 0; k < D_ / 4; ++k) {
            const float4 wv = w1p[k];
#pragma unroll
            for (int p = 0; p < 4; ++p) {
                const float4 xv = *(const float4*)&xs[rowgrp * 4 + p][k * 4];
                acc[p] += xv.x * wv.x + xv.y * wv.y + xv.z * wv.z + xv.w * wv.w;
            }
        }
#pragma unroll
        for (int p = 0; p < 4; ++p) xw1s[rowgrp * 4 + p][r] = acc[p];
    }
    __syncthreads();

    // phase B: 16 j-tiles of 64; W2 rows streamed per-lane (L1/L2-hot),
    // xw1 via LDS broadcast; stores coalesced over j.
    for (int jt = 0; jt < H_ / 64; ++jt) {
        const int j = jt * 64 + r;
        const float4* w2p = (const float4*)(W2 + (size_t)j * RW_);
        float acc[4] = {0.f, 0.f, 0.f, 0.f};
#pragma unroll
        for (int r4 = 0; r4 < RW_ / 4; ++r4) {
            const float4 wv = w2p[r4];
#pragma unroll
            for (int p = 0; p < 4; ++p) {
                const float4 xv = *(const float4*)&xw1s[rowgrp * 4 + p][r4 * 4];
                acc[p] += xv.x * wv.x + xv.y * wv.y + xv.z * wv.z + xv.w * wv.w;
            }
        }
#pragma unroll
        for (int p = 0; p < 4; ++p)
            out[(size_t)(m0 + rowgrp * 4 + p) * H_ + j] = acc[p];
    }
}

__device__ __forceinline__ float sigmoid_f(float v) {
    v = fminf(fmaxf(v, -30.f), 30.f);
    return 1.f / (1.f + __expf(-v));
}
__device__ __forceinline__ float tanh_f(float v) {
    v = fminf(fmaxf(v, -15.f), 15.f);
    const float e2 = __expf(2.f * v);
    return (e2 - 1.f) / (e2 + 1.f);
}

__global__ __launch_bounds__(256) void rec_kernel(
    const float* __restrict__ h0,    // [B, H]
    const float* __restrict__ U1,    // [RU, H]
    const float* __restrict__ U2,    // [H, RU]
    const float* __restrict__ bg,    // [H]
    const float* __restrict__ bu,    // [H]
    const float* __restrict__ zeta,  // [1]
    const float* __restrict__ nu,    // [1]
    float* __restrict__ out)         // [T, B, H], holds wx on entry
{
    __shared__ float hs[RPW][H_];              // 8 KB   current h rows
    __shared__ float part[4][RPW][RU_];        // 2 KB   phase-1 partials
    __shared__ float uh1f[RPW][RU_ + 4];       // pad 68, b128-aligned broadcast
    __shared__ float bgs[H_], bus[H_];         // 8 KB   biases

    const int tid = threadIdx.x;
    const int b0 = blockIdx.x * RPW;

    {
        const float4* hg = (const float4*)(h0 + (size_t)b0 * H_);
        float4* hv = (float4*)&hs[0][0];
#pragma unroll
        for (int k = 0; k < (RPW * H_) / 4 / 256; ++k)
            hv[tid + 256 * k] = hg[tid + 256 * k];
        ((float4*)bgs)[tid] = ((const float4*)bg)[tid];
        ((float4*)bus)[tid] = ((const float4*)bu)[tid];
    }
    const float zs = 1.f / (1.f + __expf(-zeta[0]));
    const float ns = 1.f / (1.f + __expf(-nu[0]));
    __syncthreads();

    const int r = tid & 63;   // rank lane
    const int seg = tid >> 6; // 256-wide h segment (wave-uniform)
    const float4* u1p = (const float4*)(U1 + (size_t)r * H_ + seg * 256);

    for (int t = 0; t < T_; ++t) {
        // ---- phase 1: uh1[row][r] = sum_h h[row][h] * U1[r][h] ----
        float ps[RPW] = {};
#pragma unroll 4
        for (int k = 0; k < 64; ++k) {
            const float4 uv = u1p[k];
#pragma unroll
            for (int row = 0; row < RPW; ++row) {
                const float4 hv = *(const float4*)&hs[row][seg * 256 + k * 4];
                ps[row] += hv.x * uv.x + hv.y * uv.y + hv.z * uv.z + hv.w * uv.w;
            }
        }
#pragma unroll
        for (int row = 0; row < RPW; ++row) part[seg][row][r] = ps[row];
        __syncthreads();
        if (tid < RPW * RU_) {
            const int row = tid >> 6, rr = tid & 63;
            uh1f[row][rr] = part[0][row][rr] + part[1][row][rr] +
                            part[2][row][rr] + part[3][row][rr];
        }
        __syncthreads();

        // ---- phase 2: uh[row][j] = sum_r uh1[row][r] * U2[j][r]; 4 j per thread ----
        float acc[RPW][4] = {};
#pragma unroll
        for (int r4 = 0; r4 < RU_ / 4; ++r4) {
            float4 uv[RPW];
#pragma unroll
            for (int row = 0; row < RPW; ++row)
                uv[row] = *(const float4*)&uh1f[row][r4 * 4];  // LDS broadcast
#pragma unroll
            for (int jj = 0; jj < 4; ++jj) {
                const int j = tid + 256 * jj;
                const float4 u2v = *(const float4*)(U2 + (size_t)j * RU_ + r4 * 4);
#pragma unroll
                for (int row = 0; row < RPW; ++row)
                    acc[row][jj] += u2v.x * uv[row].x + u2v.y * uv[row].y +
                                    u2v.z * uv[row].z + u2v.w * uv[row].w;
            }
        }

        // ---- elementwise gate/update; read wx from d_out[t], overwrite with h ----
        float* outt = out + (size_t)t * B_ * H_;
#pragma unroll
        for (int jj = 0; jj < 4; ++jj) {
            const int j = tid + 256 * jj;
#pragma unroll
            for (int row = 0; row < RPW; ++row) {
                const size_t idx = (size_t)(b0 + row) * H_ + j;
                const float wx = outt[idx];
                const float pre = wx + acc[row][jj];
                const float zg = sigmoid_f(pre + bgs[j]);
                const float c = tanh_f(pre + bus[j]);
                const float hn = (zs * (1.f - zg) + ns) * c + zg * hs[row][j];
                outt[idx] = hn;
                hs[row][j] = hn;
            }
        }
        __syncthreads();
    }
}

extern "C" void kernel_launch(void* const* d_in, const int* in_sizes, int n_in,
                              void* d_out, int out_size, void* d_ws, size_t ws_size,
                              hipStream_t stream) {
    const float* x = (const float*)d_in[0];
    const float* h0 = (const float*)d_in[1];
    const float* W1 = (const float*)d_in[2];
    const float* W2 = (const float*)d_in[3];
    const float* U1 = (const float*)d_in[4];
    const float* U2 = (const float*)d_in[5];
    const float* bg = (const float*)d_in[6];
    const float* bu = (const float*)d_in[7];
    const float* zeta = (const float*)d_in[8];
    const float* nu = (const float*)d_in[9];
    float* out = (float*)d_out;

    wx_kernel<<<M_ / ROWS_AB, 256, 0, stream>>>(x, W1, W2, out);
    rec_kernel<<<GC, 256, 0, stream>>>(h0, U1, U2, bg, bu, zeta, nu, out);
}